// Round 14
// baseline (61.578 us; speedup 1.0000x reference)
//
#include <hip/hip_runtime.h>
#include <math.h>

#define NB 4
#define NL1 512
#define NL2 512
#define NKD 256
#define NA 128
#define NV 256

// output layout (floats): o1 [B,L2,V], o2 [B,L1,V], w1 [B,L2,L1], w2 [B,L1,L2], score [B,L1,L2]
#define O1_OFF 0
#define O2_OFF (NB*NL2*NV)                 // 524288
#define W1_OFF (O2_OFF + NB*NL1*NV)        // 1048576
#define W2_OFF (W1_OFF + NB*NL2*NL1)       // 2097152
#define SC_OFF (W2_OFF + NB*NL1*NL2)       // 3145728

// masked score positions use -1e30f, NOT -inf (harness absmax: (-inf)-(-inf)=nan fails).
#define MASK_NEG (-1e30f)

// p1/p2 are pre-scaled by 2*log2(e) so e^{2z} = 2^{p1'+p2'}; we then store
// E = 2^clamp(p',±50) so score needs only a MUL + RCP per term (2^x·2^y = 2^(x+y)).
#define SC2LOG2E 2.8853900817779268f

#if __has_builtin(__builtin_amdgcn_exp2f)
#define EXP2F(x) __builtin_amdgcn_exp2f(x)
#else
#define EXP2F(x) __expf((x) * 0.6931471805599453f)
#endif
#if __has_builtin(__builtin_amdgcn_rcpf)
#define RCPF(x) __builtin_amdgcn_rcpf(x)
#else
#define RCPF(x) (1.0f / (x))
#endif

__device__ __forceinline__ unsigned short f2bf(float f) {
    unsigned u = __float_as_uint(f);
    u += 0x7fffu + ((u >> 16) & 1u);          // round-to-nearest-even
    return (unsigned short)(u >> 16);
}
__device__ __forceinline__ unsigned pk2bf(float a, float b) {
    return (unsigned)f2bf(a) | ((unsigned)f2bf(b) << 16);
}

// ---------------- projection: E = 2^clamp(SC2LOG2E*(K @ W + b), ±50) ----------------
// Grid extended by 512 blocks (blk >= 1024) that transpose+convert v1/v2 ONCE into
// [b][d][s] bf16 workspace, so out_matmul V staging is a pure linear copy.
__global__ __launch_bounds__(128) void proj_kernel(
    const float* __restrict__ k1, const float* __restrict__ k2,
    const float* __restrict__ W1, const float* __restrict__ b1,
    const float* __restrict__ W2, const float* __restrict__ b2,
    const float* __restrict__ v1, const float* __restrict__ v2,
    float* __restrict__ p1, float* __restrict__ p2,
    unsigned* __restrict__ v1t, unsigned* __restrict__ v2t)
{
    __shared__ float kr[4][NKD];
    __shared__ float trbuf[32][68];
    int blk = blockIdx.x;
    int tid = threadIdx.x;
    if (blk >= 1024) {
        // V transpose+bf16: tile d x s = 64 x 32
        int idx = blk - 1024;               // 0..511
        int t = idx >> 8;                   // 0: v1, 1: v2
        int rem = idx & 255;
        int b = rem >> 6;
        int rem2 = rem & 63;
        int d0 = (rem2 >> 4) * 64;          // 0..192
        int s0 = (rem2 & 15) * 32;          // 0..480
        const float* Vsrc = (t ? v2 : v1) + (size_t)b * NL2 * NV;
        unsigned* Vdst    = (t ? v2t : v1t) + (size_t)b * NV * (NL2/2);
        #pragma unroll
        for (int u = 0; u < 4; u++) {
            int i2 = tid + 128 * u;
            int r = i2 >> 4, c = i2 & 15;
            *(float4*)&trbuf[r][c*4] = *(const float4*)&Vsrc[(size_t)(s0 + r) * NV + d0 + c*4];
        }
        __syncthreads();
        #pragma unroll
        for (int u = 0; u < 8; u++) {
            int i2 = tid + 128 * u;
            int dd = i2 >> 4, c = i2 & 15;
            Vdst[(size_t)(d0 + dd) * (NL2/2) + (s0 >> 1) + c] =
                pk2bf(trbuf[2*c][dd], trbuf[2*c+1][dd]);
        }
        return;
    }
    const float *K, *W, *bias; float* P; int rowbase;
    if (blk < (NB*NL1)/4) { K = k1; W = W1; bias = b1; P = p1; rowbase = blk*4; }
    else                  { K = k2; W = W2; bias = b2; P = p2; rowbase = (blk - (NB*NL1)/4)*4; }
    for (int idx = tid; idx < 256; idx += 128) {
        int r = idx >> 6, c = idx & 63;
        *(float4*)&kr[r][c*4] = *(const float4*)&K[(rowbase + r)*NKD + c*4];
    }
    __syncthreads();
    int a = tid;
    float acc0 = bias[a], acc1 = bias[a], acc2 = bias[a], acc3 = bias[a];
    #pragma unroll 4
    for (int k = 0; k < NKD; k++) {
        float wv = W[k*NA + a];
        acc0 = fmaf(kr[0][k], wv, acc0);
        acc1 = fmaf(kr[1][k], wv, acc1);
        acc2 = fmaf(kr[2][k], wv, acc2);
        acc3 = fmaf(kr[3][k], wv, acc3);
    }
    float s0 = fminf(fmaxf(acc0 * SC2LOG2E, -50.f), 50.f);
    float s1 = fminf(fmaxf(acc1 * SC2LOG2E, -50.f), 50.f);
    float s2 = fminf(fmaxf(acc2 * SC2LOG2E, -50.f), 50.f);
    float s3 = fminf(fmaxf(acc3 * SC2LOG2E, -50.f), 50.f);
    P[(rowbase+0)*NA + a] = EXP2F(s0);
    P[(rowbase+1)*NA + a] = EXP2F(s1);
    P[(rowbase+2)*NA + a] = EXP2F(s2);
    P[(rowbase+3)*NA + a] = EXP2F(s3);
}

// ---------------- score ----------------
// score[b,i,j] = swsbs + sum_a ws2[a] * rcp(1 + E1[i][a]*E2[j][a]), masked.
// w1pre (transposed masked score) goes to WORKSPACE now (w1 output region is
// written only by the fused out_matmul -> no read/write race).
#define P1_STRIDE 132
#define P2_STRIDE 68

__global__ __launch_bounds__(256) void score_kernel(
    const float* __restrict__ p1, const float* __restrict__ p2,
    const float* __restrict__ ws, const float* __restrict__ bs,
    const int* __restrict__ len1, const int* __restrict__ len2,
    float* __restrict__ score, float* __restrict__ w1pre)
{
    __shared__ float p1t[64][P1_STRIDE];
    __shared__ float p2t[NA][P2_STRIDE];
    __shared__ float wst[NA];
    __shared__ float wsum[2];
    int b  = blockIdx.z;
    int i0 = blockIdx.y * 64, j0 = blockIdx.x * 64;
    int tid = threadIdx.x;
    if (tid < 128) {
        float w = ws[tid];
        wst[tid] = -2.0f * w;
        float v = w;
        #pragma unroll
        for (int o = 32; o > 0; o >>= 1) v += __shfl_xor(v, o);
        if ((tid & 63) == 0) wsum[tid >> 6] = v;
    }
    const float* p1src = p1 + (b*NL1 + i0)*NA;
    const float* p2src = p2 + (b*NL2 + j0)*NA;
    for (int idx = tid; idx < 2048; idx += 256) {
        int r = idx >> 5, c = idx & 31;
        *(float4*)&p1t[r][c*4] = *(const float4*)&p1src[r*NA + c*4];
    }
    for (int idx = tid; idx < 2048; idx += 256) {
        int j = idx >> 5, c = idx & 31;
        float4 t = *(const float4*)&p2src[j*NA + c*4];
        p2t[c*4+0][j] = t.x; p2t[c*4+1][j] = t.y;
        p2t[c*4+2][j] = t.z; p2t[c*4+3][j] = t.w;
    }
    __syncthreads();

    int tx = tid & 15, ty = tid >> 4;
    int il = ty*4, jl = tx*4;
    float acc[4][4] = {};
    #pragma unroll 2
    for (int a = 0; a < NA; a += 4) {
        float4 wv = *(float4*)&wst[a];
        float4 x0 = *(float4*)&p1t[il  ][a];
        float4 x1 = *(float4*)&p1t[il+1][a];
        float4 x2 = *(float4*)&p1t[il+2][a];
        float4 x3 = *(float4*)&p1t[il+3][a];
        float4 y0 = *(float4*)&p2t[a  ][jl];
        float4 y1 = *(float4*)&p2t[a+1][jl];
        float4 y2 = *(float4*)&p2t[a+2][jl];
        float4 y3 = *(float4*)&p2t[a+3][jl];
        #define TRM(r,c,xq,yq,wq) acc[r][c] = fmaf(wq, RCPF(fmaf(xq, yq, 1.0f)), acc[r][c])
        #define QROW(q, yv, wq) \
            TRM(0,0, x0.q, yv.x, wq); TRM(0,1, x0.q, yv.y, wq); TRM(0,2, x0.q, yv.z, wq); TRM(0,3, x0.q, yv.w, wq); \
            TRM(1,0, x1.q, yv.x, wq); TRM(1,1, x1.q, yv.y, wq); TRM(1,2, x1.q, yv.z, wq); TRM(1,3, x1.q, yv.w, wq); \
            TRM(2,0, x2.q, yv.x, wq); TRM(2,1, x2.q, yv.y, wq); TRM(2,2, x2.q, yv.z, wq); TRM(2,3, x2.q, yv.w, wq); \
            TRM(3,0, x3.q, yv.x, wq); TRM(3,1, x3.q, yv.y, wq); TRM(3,2, x3.q, yv.z, wq); TRM(3,3, x3.q, yv.w, wq)
        QROW(x, y0, wv.x);
        QROW(y, y1, wv.y);
        QROW(z, y2, wv.z);
        QROW(w, y3, wv.w);
        #undef QROW
        #undef TRM
    }
    float sb = wsum[0] + wsum[1] + bs[0];
    int n1 = len1[b], n2 = len2[b];
    float mv[4][4];
    #pragma unroll
    for (int di = 0; di < 4; di++) {
        int gi = i0 + il + di;
        int rp = (gi >= n1);
        #pragma unroll
        for (int dj = 0; dj < 4; dj++) {
            int gj = j0 + jl + dj;
            float val = acc[di][dj] + sb;
            int cp = (gj >= n2);
            if (rp + cp == 1) val = MASK_NEG;
            mv[di][dj] = val;
        }
    }
    #pragma unroll
    for (int di = 0; di < 4; di++) {
        float4 v = make_float4(mv[di][0], mv[di][1], mv[di][2], mv[di][3]);
        *(float4*)&score[(size_t)(b*NL1 + i0 + il + di)*NL2 + j0 + jl] = v;
    }
    #pragma unroll
    for (int dj = 0; dj < 4; dj++) {
        float4 v = make_float4(mv[0][dj], mv[1][dj], mv[2][dj], mv[3][dj]);
        *(float4*)&w1pre[((size_t)b*NL2 + j0 + jl + dj)*NL1 + i0 + il] = v;
    }
}

// ---------------- output matmuls with FUSED row-softmax ----------------
// Each block stages 64 complete K=512 rows of its W operand -- exactly the softmax
// rows (score rows for m=0/w2, w1pre rows for m=1/w1). So softmax_both is deleted:
// stage fp32 row -> 8-thread shfl max/sum (threads 8r..8r+7 are consecutive lanes,
// never cross a wave) -> exp+normalize in regs -> bf16 into LDS. d0==0 blocks also
// write the fp32 w1/w2 outputs (same 1.0f/sum arithmetic -> bit-identical).
// Full-K staging: KT=520, LDS 133 KB, one barrier, 16 MFMA steps.
typedef __attribute__((ext_vector_type(8))) short bf16x8;
typedef __attribute__((ext_vector_type(4))) float f32x4;

#define KT 520   // 512 + 8 pad (bf16); 1040 B row stride, 16B-aligned

__global__ __launch_bounds__(512) void out_matmul(
    const float* __restrict__ scoreSrc, const float* __restrict__ w1preSrc,
    const unsigned* __restrict__ v2t,   const unsigned* __restrict__ v1t,
    float* __restrict__ o2, float* __restrict__ o1,
    float* __restrict__ w2out, float* __restrict__ w1out)
{
    __shared__ unsigned short Wt[64 * KT];
    __shared__ unsigned short Vt[64 * KT];
    int z = blockIdx.z; int b = z >> 1, m = z & 1;
    const float*    Sm = (m ? w1preSrc : scoreSrc) + (size_t)b * NL1 * NL2;
    const unsigned* Vb = (m ? v1t : v2t) + (size_t)b * NV * (NL2/2);
    float* Om   = (m ? o1 : o2)       + (size_t)b * NL1 * NV;
    float* Wout = (m ? w1out : w2out) + (size_t)b * NL1 * NL2;
    int r0 = blockIdx.y * 64, d0 = blockIdx.x * 64;
    int tid = threadIdx.x;                 // 0..511
    int lane = tid & 63, wid = tid >> 6;   // 8 waves
    int ry = wid & 3, cx = wid >> 2;       // 4 row-blocks x 2 col-blocks
    int lm = lane & 15, kg = lane >> 4;
    int wr = tid >> 3, c0 = tid & 7;       // 8 threads per staged row

    // --- V staging (full K): pure uint4 copy
    {
        const unsigned* srcV = Vb + (size_t)(d0 + wr) * (NL2/2);
        unsigned short* dstV = &Vt[wr * KT];
        #pragma unroll
        for (int k = 0; k < 8; k++) {
            int c = c0 + 8 * k;
            *(uint4*)&dstV[c * 8] = *(const uint4*)&srcV[c * 4];
        }
    }
    // --- W staging with fused row-softmax (fp32 source)
    {
        const float* srcR = Sm + (size_t)(r0 + wr) * 512;
        float4 f[16];
        #pragma unroll
        for (int k = 0; k < 16; k++) f[k] = *(const float4*)&srcR[(c0 + 8*k) * 4];
        float mx = -3.4e38f;
        #pragma unroll
        for (int k = 0; k < 16; k++)
            mx = fmaxf(mx, fmaxf(fmaxf(f[k].x, f[k].y), fmaxf(f[k].z, f[k].w)));
        #pragma unroll
        for (int o = 1; o <= 4; o <<= 1) mx = fmaxf(mx, __shfl_xor(mx, o));
        float sum = 0.f;
        #pragma unroll
        for (int k = 0; k < 16; k++) {
            f[k].x = __expf(f[k].x - mx); f[k].y = __expf(f[k].y - mx);
            f[k].z = __expf(f[k].z - mx); f[k].w = __expf(f[k].w - mx);
            sum += (f[k].x + f[k].y) + (f[k].z + f[k].w);
        }
        #pragma unroll
        for (int o = 1; o <= 4; o <<= 1) sum += __shfl_xor(sum, o);
        float inv = 1.0f / sum;
        unsigned* dstW = (unsigned*)&Wt[wr * KT];
        #pragma unroll
        for (int k = 0; k < 16; k++) {
            f[k].x *= inv; f[k].y *= inv; f[k].z *= inv; f[k].w *= inv;
            int c = c0 + 8 * k;
            uint2 p = make_uint2(pk2bf(f[k].x, f[k].y), pk2bf(f[k].z, f[k].w));
            *(uint2*)&dstW[c * 2] = p;
        }
        if (d0 == 0) {
            float* orow = Wout + (size_t)(r0 + wr) * 512;
            #pragma unroll
            for (int k = 0; k < 16; k++)
                *(float4*)&orow[(c0 + 8*k) * 4] = f[k];
        }
    }
    __syncthreads();

    const unsigned short* Wf  = &Wt[(ry * 16 + lm) * KT];
    const unsigned short* Vlo = &Vt[(cx * 32 + lm) * KT];
    const unsigned short* Vhi = Vlo + 16 * KT;

    f32x4 acc0 = {0.f,0.f,0.f,0.f}, acc1 = {0.f,0.f,0.f,0.f};
    #pragma unroll 4
    for (int t = 0; t < 16; t++) {
        int s0 = t * 32 + 8 * kg;
        bf16x8 fa  = *(const bf16x8*)(Wf  + s0);
        bf16x8 fb0 = *(const bf16x8*)(Vlo + s0);
        bf16x8 fb1 = *(const bf16x8*)(Vhi + s0);
        acc0 = __builtin_amdgcn_mfma_f32_16x16x32_bf16(fa, fb0, acc0, 0, 0, 0);
        acc1 = __builtin_amdgcn_mfma_f32_16x16x32_bf16(fa, fb1, acc1, 0, 0, 0);
    }

    int rlo = r0 + ry * 16 + 4 * kg;
    int clo = d0 + cx * 32 + lm;
    #pragma unroll
    for (int e = 0; e < 4; e++) {
        Om[(size_t)(rlo + e) * NV + clo]      = acc0[e];
        Om[(size_t)(rlo + e) * NV + clo + 16] = acc1[e];
    }
}

extern "C" void kernel_launch(void* const* d_in, const int* in_sizes, int n_in,
                              void* d_out, int out_size, void* d_ws, size_t ws_size,
                              hipStream_t stream) {
    const float* k1  = (const float*)d_in[0];
    const float* k2  = (const float*)d_in[1];
    const float* v1  = (const float*)d_in[2];
    const float* v2  = (const float*)d_in[3];
    const float* W1  = (const float*)d_in[4];
    const float* b1  = (const float*)d_in[5];
    const float* W2  = (const float*)d_in[6];
    const float* b2  = (const float*)d_in[7];
    const float* wsv = (const float*)d_in[8];
    const float* bsp = (const float*)d_in[9];
    const int* len1  = (const int*)d_in[10];
    const int* len2  = (const int*)d_in[11];

    float* out   = (float*)d_out;
    float* o1    = out + O1_OFF;
    float* o2    = out + O2_OFF;
    float* w1    = out + W1_OFF;
    float* w2    = out + W2_OFF;
    float* score = out + SC_OFF;

    // workspace (8 MB): p1, p2 (fp32 E), w1pre (fp32), v2t, v1t (bf16-packed)
    float* p1       = (float*)d_ws;               // 262144 floats
    float* p2       = p1 + NB*NL1*NA;             // 262144 floats
    float* w1pre    = p2 + NB*NL2*NA;             // 1048576 floats
    unsigned* v2t   = (unsigned*)(w1pre + (size_t)NB*NL2*NL1);  // 262144 u32
    unsigned* v1t   = v2t + (size_t)NB*NV*(NL2/2);              // 262144 u32

    proj_kernel<<<dim3((NB*NL1)/4 + (NB*NL2)/4 + 512), 128, 0, stream>>>(
        k1, k2, W1, b1, W2, b2, v1, v2, p1, p2, v1t, v2t);
    score_kernel<<<dim3(NL2/64, NL1/64, NB), 256, 0, stream>>>(p1, p2, wsv, bsp, len1, len2, score, w1pre);
    out_matmul<<<dim3(NV/64, NL1/64, NB*2), 512, 0, stream>>>(score, w1pre, v2t, v1t, o2, o1, w2, w1);
}

// Round 15
// 58.233 us; speedup vs baseline: 1.0574x; 1.0574x over previous
//
#include <hip/hip_runtime.h>
#include <math.h>

#define NB 4
#define NL1 512
#define NL2 512
#define NKD 256
#define NA 128
#define NV 256

// output layout (floats): o1 [B,L2,V], o2 [B,L1,V], w1 [B,L2,L1], w2 [B,L1,L2], score [B,L1,L2]
#define O1_OFF 0
#define O2_OFF (NB*NL2*NV)                 // 524288
#define W1_OFF (O2_OFF + NB*NL1*NV)        // 1048576
#define W2_OFF (W1_OFF + NB*NL2*NL1)       // 2097152
#define SC_OFF (W2_OFF + NB*NL1*NL2)       // 3145728

// masked score positions use -1e30f, NOT -inf (harness absmax: (-inf)-(-inf)=nan fails).
#define MASK_NEG (-1e30f)

// p1/p2 are pre-scaled by 2*log2(e) so e^{2z} = 2^{p1'+p2'}; we then store
// E = 2^clamp(p',±50) so score needs only a MUL + RCP per term (2^x·2^y = 2^(x+y)).
#define SC2LOG2E 2.8853900817779268f

#if __has_builtin(__builtin_amdgcn_exp2f)
#define EXP2F(x) __builtin_amdgcn_exp2f(x)
#else
#define EXP2F(x) __expf((x) * 0.6931471805599453f)
#endif
#if __has_builtin(__builtin_amdgcn_rcpf)
#define RCPF(x) __builtin_amdgcn_rcpf(x)
#else
#define RCPF(x) (1.0f / (x))
#endif

__device__ __forceinline__ unsigned short f2bf(float f) {
    unsigned u = __float_as_uint(f);
    u += 0x7fffu + ((u >> 16) & 1u);          // round-to-nearest-even
    return (unsigned short)(u >> 16);
}
__device__ __forceinline__ unsigned pk2bf(float a, float b) {
    return (unsigned)f2bf(a) | ((unsigned)f2bf(b) << 16);
}

// ---------------- projection: E = 2^clamp(SC2LOG2E*(K @ W + b), ±50) ----------------
// Grid extended by 512 blocks (blk >= 1024) that transpose+convert v1/v2 ONCE into
// [b][d][s] bf16 workspace, so out_matmul V staging is a pure linear copy.
__global__ __launch_bounds__(128) void proj_kernel(
    const float* __restrict__ k1, const float* __restrict__ k2,
    const float* __restrict__ W1, const float* __restrict__ b1,
    const float* __restrict__ W2, const float* __restrict__ b2,
    const float* __restrict__ v1, const float* __restrict__ v2,
    float* __restrict__ p1, float* __restrict__ p2,
    unsigned* __restrict__ v1t, unsigned* __restrict__ v2t)
{
    __shared__ float kr[4][NKD];
    __shared__ float trbuf[32][68];
    int blk = blockIdx.x;
    int tid = threadIdx.x;
    if (blk >= 1024) {
        // V transpose+bf16: tile d x s = 64 x 32
        int idx = blk - 1024;               // 0..511
        int t = idx >> 8;                   // 0: v1, 1: v2
        int rem = idx & 255;
        int b = rem >> 6;
        int rem2 = rem & 63;
        int d0 = (rem2 >> 4) * 64;          // 0..192
        int s0 = (rem2 & 15) * 32;          // 0..480
        const float* Vsrc = (t ? v2 : v1) + (size_t)b * NL2 * NV;
        unsigned* Vdst    = (t ? v2t : v1t) + (size_t)b * NV * (NL2/2);
        #pragma unroll
        for (int u = 0; u < 4; u++) {
            int i2 = tid + 128 * u;
            int r = i2 >> 4, c = i2 & 15;
            *(float4*)&trbuf[r][c*4] = *(const float4*)&Vsrc[(size_t)(s0 + r) * NV + d0 + c*4];
        }
        __syncthreads();
        #pragma unroll
        for (int u = 0; u < 8; u++) {
            int i2 = tid + 128 * u;
            int dd = i2 >> 4, c = i2 & 15;
            Vdst[(size_t)(d0 + dd) * (NL2/2) + (s0 >> 1) + c] =
                pk2bf(trbuf[2*c][dd], trbuf[2*c+1][dd]);
        }
        return;
    }
    const float *K, *W, *bias; float* P; int rowbase;
    if (blk < (NB*NL1)/4) { K = k1; W = W1; bias = b1; P = p1; rowbase = blk*4; }
    else                  { K = k2; W = W2; bias = b2; P = p2; rowbase = (blk - (NB*NL1)/4)*4; }
    for (int idx = tid; idx < 256; idx += 128) {
        int r = idx >> 6, c = idx & 63;
        *(float4*)&kr[r][c*4] = *(const float4*)&K[(rowbase + r)*NKD + c*4];
    }
    __syncthreads();
    int a = tid;
    float acc0 = bias[a], acc1 = bias[a], acc2 = bias[a], acc3 = bias[a];
    #pragma unroll 4
    for (int k = 0; k < NKD; k++) {
        float wv = W[k*NA + a];
        acc0 = fmaf(kr[0][k], wv, acc0);
        acc1 = fmaf(kr[1][k], wv, acc1);
        acc2 = fmaf(kr[2][k], wv, acc2);
        acc3 = fmaf(kr[3][k], wv, acc3);
    }
    float s0 = fminf(fmaxf(acc0 * SC2LOG2E, -50.f), 50.f);
    float s1 = fminf(fmaxf(acc1 * SC2LOG2E, -50.f), 50.f);
    float s2 = fminf(fmaxf(acc2 * SC2LOG2E, -50.f), 50.f);
    float s3 = fminf(fmaxf(acc3 * SC2LOG2E, -50.f), 50.f);
    P[(rowbase+0)*NA + a] = EXP2F(s0);
    P[(rowbase+1)*NA + a] = EXP2F(s1);
    P[(rowbase+2)*NA + a] = EXP2F(s2);
    P[(rowbase+3)*NA + a] = EXP2F(s3);
}

// ---------------- score ----------------
// score[b,i,j] = swsbs + sum_a ws2[a] * rcp(1 + E1[i][a]*E2[j][a]), masked.
// R12 (4x4 ILP, 2 blk/CU) == R10 (2x2, 4 blk/CU) == ~13us: need ILP *and* TLP together.
// a-dim processed in two 64-wide chunks -> LDS 69->35 KB -> 4 blocks/CU = 4 waves/SIMD
// with the 16-chain inner loop intact. Accumulators carry across chunks.
#define PC_STRIDE 68

__global__ __launch_bounds__(256, 4) void score_kernel(
    const float* __restrict__ p1, const float* __restrict__ p2,
    const float* __restrict__ ws, const float* __restrict__ bs,
    const int* __restrict__ len1, const int* __restrict__ len2,
    float* __restrict__ score, float* __restrict__ w1pre)
{
    __shared__ float p1t[64][PC_STRIDE];
    __shared__ float p2t[64][PC_STRIDE];
    __shared__ float wst[NA];
    __shared__ float wsum[2];
    int b  = blockIdx.z;
    int i0 = blockIdx.y * 64, j0 = blockIdx.x * 64;
    int tid = threadIdx.x;
    if (tid < 128) {
        float w = ws[tid];
        wst[tid] = -2.0f * w;
        float v = w;
        #pragma unroll
        for (int o = 32; o > 0; o >>= 1) v += __shfl_xor(v, o);
        if ((tid & 63) == 0) wsum[tid >> 6] = v;
    }
    const float* p1src = p1 + (b*NL1 + i0)*NA;
    const float* p2src = p2 + (b*NL2 + j0)*NA;

    int tx = tid & 15, ty = tid >> 4;
    int il = ty*4, jl = tx*4;
    float acc[4][4] = {};

    for (int ac = 0; ac < NA; ac += 64) {
        if (ac) __syncthreads();   // all waves done with previous chunk
        // stage p1 chunk: 64 rows x 16 float4 (256B contiguous per row)
        #pragma unroll
        for (int u = 0; u < 4; u++) {
            int idx = tid + 256 * u;
            int r = idx >> 4, c = idx & 15;
            *(float4*)&p1t[r][c*4] = *(const float4*)&p1src[r*NA + ac + c*4];
        }
        // stage p2 chunk transposed: p2t[a_local][j]
        #pragma unroll
        for (int u = 0; u < 4; u++) {
            int idx = tid + 256 * u;
            int j = idx >> 4, c = idx & 15;
            float4 t = *(const float4*)&p2src[j*NA + ac + c*4];
            p2t[c*4+0][j] = t.x; p2t[c*4+1][j] = t.y;
            p2t[c*4+2][j] = t.z; p2t[c*4+3][j] = t.w;
        }
        __syncthreads();
        #pragma unroll 2
        for (int a = 0; a < 64; a += 4) {
            float4 wv = *(float4*)&wst[ac + a];
            float4 x0 = *(float4*)&p1t[il  ][a];
            float4 x1 = *(float4*)&p1t[il+1][a];
            float4 x2 = *(float4*)&p1t[il+2][a];
            float4 x3 = *(float4*)&p1t[il+3][a];
            float4 y0 = *(float4*)&p2t[a  ][jl];
            float4 y1 = *(float4*)&p2t[a+1][jl];
            float4 y2 = *(float4*)&p2t[a+2][jl];
            float4 y3 = *(float4*)&p2t[a+3][jl];
            #define TRM(r,c,xq,yq,wq) acc[r][c] = fmaf(wq, RCPF(fmaf(xq, yq, 1.0f)), acc[r][c])
            #define QROW(q, yv, wq) \
                TRM(0,0, x0.q, yv.x, wq); TRM(0,1, x0.q, yv.y, wq); TRM(0,2, x0.q, yv.z, wq); TRM(0,3, x0.q, yv.w, wq); \
                TRM(1,0, x1.q, yv.x, wq); TRM(1,1, x1.q, yv.y, wq); TRM(1,2, x1.q, yv.z, wq); TRM(1,3, x1.q, yv.w, wq); \
                TRM(2,0, x2.q, yv.x, wq); TRM(2,1, x2.q, yv.y, wq); TRM(2,2, x2.q, yv.z, wq); TRM(2,3, x2.q, yv.w, wq); \
                TRM(3,0, x3.q, yv.x, wq); TRM(3,1, x3.q, yv.y, wq); TRM(3,2, x3.q, yv.z, wq); TRM(3,3, x3.q, yv.w, wq)
            QROW(x, y0, wv.x);
            QROW(y, y1, wv.y);
            QROW(z, y2, wv.z);
            QROW(w, y3, wv.w);
            #undef QROW
            #undef TRM
        }
    }
    float sb = wsum[0] + wsum[1] + bs[0];
    int n1 = len1[b], n2 = len2[b];
    float mv[4][4];
    #pragma unroll
    for (int di = 0; di < 4; di++) {
        int gi = i0 + il + di;
        int rp = (gi >= n1);
        #pragma unroll
        for (int dj = 0; dj < 4; dj++) {
            int gj = j0 + jl + dj;
            float val = acc[di][dj] + sb;
            int cp = (gj >= n2);
            if (rp + cp == 1) val = MASK_NEG;
            mv[di][dj] = val;
        }
    }
    #pragma unroll
    for (int di = 0; di < 4; di++) {
        float4 v = make_float4(mv[di][0], mv[di][1], mv[di][2], mv[di][3]);
        *(float4*)&score[(size_t)(b*NL1 + i0 + il + di)*NL2 + j0 + jl] = v;
    }
    #pragma unroll
    for (int dj = 0; dj < 4; dj++) {
        float4 v = make_float4(mv[0][dj], mv[1][dj], mv[2][dj], mv[3][dj]);
        *(float4*)&w1pre[((size_t)b*NL2 + j0 + jl + dj)*NL1 + i0 + il] = v;
    }
}

// ---------------- merged softmax: one WAVE per row; also writes bf16 copies ----------------
__global__ __launch_bounds__(256) void softmax_both(const float* __restrict__ score,
                                                    float* __restrict__ w2,
                                                    float* __restrict__ w1,
                                                    unsigned* __restrict__ w2bf,
                                                    unsigned* __restrict__ w1bf)
{
    int row = blockIdx.x * 4 + (threadIdx.x >> 6);
    int lane = threadIdx.x & 63;
    const float* s; float* d; unsigned* dbf;
    if (row < NB*NL1) {
        s = score + (size_t)row * NL2; d = w2 + (size_t)row * NL2;
        dbf = w2bf + (size_t)row * (NL2/2);
    } else {
        size_t r = row - NB*NL1;
        s = w1 + r * NL1; d = w1 + r * NL1;
        dbf = w1bf + r * (NL1/2);
    }
    float4 v0 = *(const float4*)&s[lane * 4];
    float4 v1 = *(const float4*)&s[256 + lane * 4];
    float m = fmaxf(fmaxf(fmaxf(v0.x, v0.y), fmaxf(v0.z, v0.w)),
                    fmaxf(fmaxf(v1.x, v1.y), fmaxf(v1.z, v1.w)));
    #pragma unroll
    for (int o = 32; o > 0; o >>= 1) m = fmaxf(m, __shfl_xor(m, o));
    float4 e0, e1;
    e0.x = __expf(v0.x - m); e0.y = __expf(v0.y - m);
    e0.z = __expf(v0.z - m); e0.w = __expf(v0.w - m);
    e1.x = __expf(v1.x - m); e1.y = __expf(v1.y - m);
    e1.z = __expf(v1.z - m); e1.w = __expf(v1.w - m);
    float sum = (e0.x + e0.y) + (e0.z + e0.w) + (e1.x + e1.y) + (e1.z + e1.w);
    #pragma unroll
    for (int o = 32; o > 0; o >>= 1) sum += __shfl_xor(sum, o);
    float inv = 1.0f / sum;
    e0.x *= inv; e0.y *= inv; e0.z *= inv; e0.w *= inv;
    e1.x *= inv; e1.y *= inv; e1.z *= inv; e1.w *= inv;
    *(float4*)&d[lane * 4] = e0;
    *(float4*)&d[256 + lane * 4] = e1;
    uint2 lo = make_uint2(pk2bf(e0.x, e0.y), pk2bf(e0.z, e0.w));
    uint2 hi = make_uint2(pk2bf(e1.x, e1.y), pk2bf(e1.z, e1.w));
    *(uint2*)&dbf[lane * 2] = lo;
    *(uint2*)&dbf[128 + lane * 2] = hi;
}

// ---------------- output matmuls (bf16 MFMA; staging = pure uint4 copy) ----------------
typedef __attribute__((ext_vector_type(8))) short bf16x8;
typedef __attribute__((ext_vector_type(4))) float f32x4;

#define KT 264   // 256 + 8 pad (bf16); 528 B row stride, 16B-aligned

__global__ __launch_bounds__(512) void out_matmul(
    const unsigned* __restrict__ w2bf, const unsigned* __restrict__ w1bf,
    const unsigned* __restrict__ v2t,  const unsigned* __restrict__ v1t,
    float* __restrict__ o2, float* __restrict__ o1)
{
    __shared__ unsigned short Wt[64 * KT];
    __shared__ unsigned short Vt[64 * KT];
    int z = blockIdx.z; int b = z >> 1, m = z & 1;
    const unsigned* Wb = (m ? w1bf : w2bf) + (size_t)b * NL1 * (NL2/2);
    const unsigned* Vb = (m ? v1t : v2t)   + (size_t)b * NV * (NL2/2);
    float*          Om = (m ? o1 : o2)     + (size_t)b * NL1 * NV;
    int r0 = blockIdx.y * 64, d0 = blockIdx.x * 64;
    int tid = threadIdx.x;                 // 0..511
    int lane = tid & 63, wid = tid >> 6;   // 8 waves
    int ry = wid & 3, cx = wid >> 2;       // 4 row-blocks x 2 col-blocks
    int lm = lane & 15, kg = lane >> 4;

    const unsigned short* Wf  = &Wt[(ry * 16 + lm) * KT];
    const unsigned short* Vlo = &Vt[(cx * 32 + lm) * KT];
    const unsigned short* Vhi = Vlo + 16 * KT;

    f32x4 acc0 = {0.f,0.f,0.f,0.f}, acc1 = {0.f,0.f,0.f,0.f};

    int wr = tid >> 3, c0 = tid & 7;
    for (int h = 0; h < 2; h++) {
        if (h) __syncthreads();                  // all waves done reading previous half
        // stage W+V halves: pure uint4 copy, 4 chunks each per thread
        const unsigned* srcW = Wb + (size_t)(r0 + wr) * (NL2/2) + h * 128;
        const unsigned* srcV = Vb + (size_t)(d0 + wr) * (NL2/2) + h * 128;
        unsigned short* dstW = &Wt[wr * KT];
        unsigned short* dstV = &Vt[wr * KT];
        #pragma unroll
        for (int k = 0; k < 4; k++) {
            int c = c0 + 8 * k;
            *(uint4*)&dstW[c * 8] = *(const uint4*)&srcW[c * 4];
            *(uint4*)&dstV[c * 8] = *(const uint4*)&srcV[c * 4];
        }
        __syncthreads();
        #pragma unroll 4
        for (int t = 0; t < 8; t++) {
            int s0 = t * 32 + 8 * kg;
            bf16x8 fa  = *(const bf16x8*)(Wf  + s0);
            bf16x8 fb0 = *(const bf16x8*)(Vlo + s0);
            bf16x8 fb1 = *(const bf16x8*)(Vhi + s0);
            acc0 = __builtin_amdgcn_mfma_f32_16x16x32_bf16(fa, fb0, acc0, 0, 0, 0);
            acc1 = __builtin_amdgcn_mfma_f32_16x16x32_bf16(fa, fb1, acc1, 0, 0, 0);
        }
    }

    int rlo = r0 + ry * 16 + 4 * kg;
    int clo = d0 + cx * 32 + lm;
    #pragma unroll
    for (int e = 0; e < 4; e++) {
        Om[(size_t)(rlo + e) * NV + clo]      = acc0[e];
        Om[(size_t)(rlo + e) * NV + clo + 16] = acc1[e];
    }
}

extern "C" void kernel_launch(void* const* d_in, const int* in_sizes, int n_in,
                              void* d_out, int out_size, void* d_ws, size_t ws_size,
                              hipStream_t stream) {
    const float* k1  = (const float*)d_in[0];
    const float* k2  = (const float*)d_in[1];
    const float* v1  = (const float*)d_in[2];
    const float* v2  = (const float*)d_in[3];
    const float* W1  = (const float*)d_in[4];
    const float* b1  = (const float*)d_in[5];
    const float* W2  = (const float*)d_in[6];
    const float* b2  = (const float*)d_in[7];
    const float* wsv = (const float*)d_in[8];
    const float* bsp = (const float*)d_in[9];
    const int* len1  = (const int*)d_in[10];
    const int* len2  = (const int*)d_in[11];

    float* out   = (float*)d_out;
    float* o1    = out + O1_OFF;
    float* o2    = out + O2_OFF;
    float* w1    = out + W1_OFF;
    float* w2    = out + W2_OFF;
    float* score = out + SC_OFF;

    // workspace: p1, p2 (fp32), then bf16-packed regions (total ~8 MB)
    float* p1       = (float*)d_ws;               // 262144 floats
    float* p2       = p1 + NB*NL1*NA;             // 262144 floats
    unsigned* w2bf  = (unsigned*)(p2 + NB*NL2*NA);        // 524288 u32
    unsigned* w1bf  = w2bf + (size_t)NB*NL1*(NL2/2);      // 524288 u32
    unsigned* v2t   = w1bf + (size_t)NB*NL2*(NL1/2);      // 262144 u32
    unsigned* v1t   = v2t + (size_t)NB*NV*(NL2/2);        // 262144 u32

    proj_kernel<<<dim3((NB*NL1)/4 + (NB*NL2)/4 + 512), 128, 0, stream>>>(
        k1, k2, W1, b1, W2, b2, v1, v2, p1, p2, v1t, v2t);
    score_kernel<<<dim3(NL2/64, NL1/64, NB), 256, 0, stream>>>(p1, p2, wsv, bsp, len1, len2, score, w1);
    softmax_both<<<dim3((NB*NL1 + NB*NL2)/4), 256, 0, stream>>>(score, w2, w1, w2bf, w1bf);
    out_matmul<<<dim3(NV/64, NL1/64, NB*2), 512, 0, stream>>>(w2bf, w1bf, v2t, v1t, o2, o1);
}